// Round 1
// 1745.180 us; speedup vs baseline: 1.9653x; 1.9653x over previous
//
#include <hip/hip_runtime.h>
#include <hip/hip_bf16.h>
#include <cstdint>

typedef short v8s __attribute__((ext_vector_type(8)));
typedef float f32x4 __attribute__((ext_vector_type(4)));
typedef float f4 __attribute__((ext_vector_type(4)));

#define BB 512
#define TT 256
#define DD 128
#define HH 512
#define GINW 768

static __device__ __forceinline__ unsigned short f2b(float f) {
  __hip_bfloat16 h = __float2bfloat16(f);
  return __builtin_bit_cast(unsigned short, h);
}
static __device__ __forceinline__ unsigned long long pk4(float a, float b, float c, float d) {
  return (unsigned long long)f2b(a) | ((unsigned long long)f2b(b) << 16)
       | ((unsigned long long)f2b(c) << 32) | ((unsigned long long)f2b(d) << 48);
}
static __device__ __forceinline__ float sigm(float v) { return 1.f / (1.f + __expf(-v)); }
static __device__ __forceinline__ float tanh_f(float v) { return 1.f - 2.f / (__expf(2.f * v) + 1.f); }

#define MFMA(A, B, C) __builtin_amdgcn_mfma_f32_16x16x32_bf16((A), (B), (C), 0, 0, 0)

// Exchange buffers use FRAGMENT-NATIVE layout: element (row r, col c) of the
// 32x512 group tile lives at short-offset  (c>>5)*1024 + ((c&31)>>3)*256 + r*8 + (c&7).
// -> each lane's A-fragment is 16 contiguous bytes (one dwordx4), and each
// producer block's 32x32 slice is one contiguous 2KB region (ks = j).
// Loads are device/system-scope (sc0 sc1) so they bypass L1/L2 and read the
// L3 coherence point, matching the proven agent-scope atomic-store exports.
static __device__ __forceinline__ void load_frags16T(const unsigned short* base, v8s fr[16]) {
#pragma unroll
  for (int ks = 0; ks < 16; ++ks) {
    asm volatile("global_load_dwordx4 %0, %1, off sc0 sc1"
                 : "=v"(fr[ks]) : "v"(base + ks * 1024));
  }
  asm volatile("s_waitcnt vmcnt(0)" ::: "memory");
  __builtin_amdgcn_sched_barrier(0);   // rule 18: keep MFMAs below the waitcnt
}

// Persistent kernel, plain launch, grid = 256 = CU count.
// Co-residency (barrier safety): LDS ~55KB -> <=2 blocks/CU; VGPR<=512 -> >=1
// block/CU; capacity >= 256 blocks >= grid => all blocks resident.
// 16 groups (g=bid&15) x 16 column-slices (j=bid>>4); group g owns batch rows
// [32g,32g+32); block (g,j) owns h-cols [32j,32j+32). Weights in VGPRs.
// Exchange: relaxed agent 8B atomic stores -> L3; reads via sc0sc1 dwordx4.
// Barrier: relaxed per-block epoch flags @128B stride; ALL waves poll (no
// post-poll __syncthreads) so each wave starts its fragment loads the moment
// it sees all 15 peer flags. Waits overlapped: p-wait absorbs elementwise
// staging of t+1; h-wait absorbs x-part MFMAs of t+1.
__global__ __launch_bounds__(256, 1) void k_seq(
    const float* __restrict__ x, const float* __restrict__ xl,
    const float* __restrict__ mk, const float* __restrict__ de,
    const float* __restrict__ xmean,
    const float* __restrict__ Wz, const float* __restrict__ bz,
    const float* __restrict__ Wr, const float* __restrict__ br,
    const float* __restrict__ Wn, const float* __restrict__ bn,
    const float* __restrict__ Wgx, const float* __restrict__ bgx,
    const float* __restrict__ Wgh, const float* __restrict__ bgh,
    unsigned short* __restrict__ PBUF, unsigned short* __restrict__ HBUF,
    unsigned int* __restrict__ BAR, float* __restrict__ out)
{
  __shared__ unsigned short XA[2][32 * 264];   // [x_tilde(128)|m(128)] bf16 double-buf
  __shared__ unsigned short DLs[2][32 * 136];  // delta(t+1) bf16 double-buf
  __shared__ unsigned short sl[32 * 36];       // own 32x32 slice repack for export
  __shared__ float cw[128], cbx[128], cxm[128];

  const int bid = blockIdx.x;
  const int g = bid & 15, j = bid >> 4;
  const int tid = threadIdx.x, wave = tid >> 6, lane = tid & 63;
  const int q = lane >> 4, ln = lane & 15;
  const int mh = wave >> 1, nh = wave & 1;
  const int b0 = g * 32, c0 = j * 32;
  const int mrow = mh * 16 + q * 4;            // +rg = local batch row (C layout)
  const int arow = mh * 16 + ln;               // A-fragment row
  const int ccol = c0 + nh * 16 + ln;          // global h column this lane owns

  if (tid < 128) { cw[tid] = Wgx[tid * DD + tid]; cbx[tid] = bgx[tid]; cxm[tid] = xmean[tid]; }

  const float bzv = bz[ccol], brv = br[ccol], bnv = bn[ccol], bgv = bgh[ccol];

  // ---- weight fragments (one-time; bf16 in VGPRs) ----
  v8s zb[16], rb[16], nb[16];        // h-part cols [128:640) of GIN, K=512
  {
    const size_t wro = (size_t)ccol * GINW + 128;
#pragma unroll
    for (int ks = 0; ks < 16; ++ks) {
      const float* pz = Wz + wro + ks * 32 + q * 8;
      const float* pr = Wr + wro + ks * 32 + q * 8;
      const float* pn = Wn + wro + ks * 32 + q * 8;
      v8s vz, vr, vn;
#pragma unroll
      for (int e = 0; e < 8; ++e) {
        vz[e] = (short)f2b(pz[e]); vr[e] = (short)f2b(pr[e]); vn[e] = (short)f2b(pn[e]);
      }
      zb[ks] = vz; rb[ks] = vr; nb[ks] = vn;
    }
  }
  v8s xzb[8], xrb[8], xnb[8];        // x-part [0:128) + m-part [640:768), K'=256
  {
    const size_t wro = (size_t)ccol * GINW;
#pragma unroll
    for (int ks = 0; ks < 8; ++ks) {
      const size_t o = wro + ((ks < 4) ? (size_t)(ks * 32 + q * 8) : (size_t)(512 + ks * 32 + q * 8));
      const float* pz = Wz + o; const float* pr = Wr + o; const float* pn = Wn + o;
      v8s vz, vr, vn;
#pragma unroll
      for (int e = 0; e < 8; ++e) {
        vz[e] = (short)f2b(pz[e]); vr[e] = (short)f2b(pr[e]); vn[e] = (short)f2b(pn[e]);
      }
      xzb[ks] = vz; xrb[ks] = vr; xnb[ks] = vn;
    }
  }
  v8s gb[4];                         // Wgh own cols, K=128
  {
    const size_t wro = (size_t)ccol * DD;
#pragma unroll
    for (int ks = 0; ks < 4; ++ks) {
      const float* pg = Wgh + wro + ks * 32 + q * 8;
      v8s vg;
#pragma unroll
      for (int e = 0; e < 8; ++e) vg[e] = (short)f2b(pg[e]);
      gb[ks] = vg;
    }
  }

  float h_own[4] = {0.f, 0.f, 0.f, 0.f};
  unsigned int ep = 0;
  unsigned short* pb = PBUF + (size_t)(g * 2) * 32 * HH;
  unsigned short* hb = HBUF + (size_t)(g * 2) * 32 * HH;
  unsigned int* flg = BAR + g * 512;           // 16 flags @ 128B stride per group
  unsigned int* myf = flg + j * 32;

  const int erow = tid >> 3, ed0 = (tid & 7) * 16;
  const size_t xrowb = (size_t)(b0 + erow) * TT * DD;

  // ---- elementwise staging of XA(tx), DL=delta(tx+1) into buffer bp ----
  auto stage = [&](int bp, int tx) {
    const size_t bt = xrowb + (size_t)tx * DD + ed0;
    const int tn = (tx + 1 < TT) ? (tx + 1) : (TT - 1);
    const size_t bn_ = xrowb + (size_t)tn * DD + ed0;
    const f4* px  = (const f4*)(x + bt);
    const f4* pxl = (const f4*)(xl + bt);
    const f4* pmk = (const f4*)(mk + bt);
    const f4* pdl = (const f4*)(de + bt);
    const f4* pdn = (const f4*)(de + bn_);
#pragma unroll
    for (int c = 0; c < 4; ++c) {
      const int d = ed0 + c * 4;
      f4 wv  = *(const f4*)&cw[d];
      f4 bv  = *(const f4*)&cbx[d];
      f4 xmv = *(const f4*)&cxm[d];
      f4 xv = px[c], xlv = pxl[c], mkv = pmk[c], dv = pdl[c], dnv = pdn[c];
      float xt[4];
#pragma unroll
      for (int e = 0; e < 4; ++e) {
        float gx = __expf(-fmaxf(0.f, dv[e] * wv[e] + bv[e]));
        float q1 = gx * (xlv[e] - xmv[e]) + xmv[e];
        xt[e] = q1 + mkv[e] * (xv[e] - q1);
      }
      *(unsigned long long*)&XA[bp][erow * 264 + d]       = pk4(xt[0], xt[1], xt[2], xt[3]);
      *(unsigned long long*)&XA[bp][erow * 264 + 128 + d] = pk4(mkv[0], mkv[1], mkv[2], mkv[3]);
      *(unsigned long long*)&DLs[bp][erow * 136 + d]      = pk4(dnv[0], dnv[1], dnv[2], dnv[3]);
    }
  };

  // x-part GEMMs over buffer bp -> fresh accumulators
  f32x4 azc, arc, anc, agc;
  auto xgemm = [&](int bp) {
    f32x4 z_ = {0.f,0.f,0.f,0.f}, r_ = {0.f,0.f,0.f,0.f};
    f32x4 n_ = {0.f,0.f,0.f,0.f}, g_ = {0.f,0.f,0.f,0.f};
#pragma unroll
    for (int ks = 0; ks < 8; ++ks) {
      v8s a = *(const v8s*)&XA[bp][arow * 264 + ks * 32 + q * 8];
      z_ = MFMA(a, xzb[ks], z_);
      r_ = MFMA(a, xrb[ks], r_);
      n_ = MFMA(a, xnb[ks], n_);
    }
#pragma unroll
    for (int ks = 0; ks < 4; ++ks) {
      v8s a = *(const v8s*)&DLs[bp][arow * 136 + ks * 32 + q * 8];
      g_ = MFMA(a, gb[ks], g_);
    }
    azc = z_; arc = r_; anc = n_; agc = g_;
  };

  // Export own 32x32 slice to fragment-native layout: ks region = j, one
  // contiguous 2KB block; 256 threads x one coalesced 8B agent store.
  auto export_sl = [&](unsigned short* dst) {   // dst = group buf + parity offset
    const int h4 = tid & 1, row = (tid >> 1) & 31, qq = tid >> 6;
    unsigned long long v = *(unsigned long long*)&sl[row * 36 + qq * 8 + h4 * 4];
    __hip_atomic_store((unsigned long long*)(dst + (size_t)(j * 1024 + qq * 256 + row * 8 + h4 * 4)),
                       v, __ATOMIC_RELAXED, __HIP_MEMORY_SCOPE_AGENT);
  };
  // All waves poll (lanes 0..15 each own one peer flag) -> no barrier needed
  // after the poll; each wave proceeds to its loads independently.
  auto poll = [&]() {
    if (lane < 16 && lane != j) {
      const unsigned int* fp = flg + lane * 32;
      while (__hip_atomic_load(fp, __ATOMIC_RELAXED, __HIP_MEMORY_SCOPE_AGENT) < ep)
        __builtin_amdgcn_s_sleep(1);
    }
    __builtin_amdgcn_sched_barrier(0);   // keep subsequent loads below the poll
  };

  // ---- prologue: stage t=0, compute its x-part ----
  __syncthreads();                 // cw/cbx/cxm visible to all waves
  stage(0, 0);
  __syncthreads();
  xgemm(0);

  for (int t = 0; t < TT; ++t) {
    const int par = t & 1;
    // ---- phase A: h-part of z, r (coalesced frags direct from L3) ----
    if (t > 0) {
      v8s fr[16];
      load_frags16T(hb + (size_t)((t - 1) & 1) * 32 * HH + q * 256 + arow * 8, fr);
#pragma unroll
      for (int ks = 0; ks < 16; ++ks) {
        azc = MFMA(fr[ks], zb[ks], azc);
        arc = MFMA(fr[ks], rb[ks], arc);
      }
    }
    float zz[4];
#pragma unroll
    for (int rg = 0; rg < 4; ++rg) {
      float z = sigm(azc[rg] + bzv);
      float r = sigm(arc[rg] + brv);
      zz[rg] = z;
      sl[(mrow + rg) * 36 + nh * 16 + ln] = f2b(r * h_own[rg]);
    }
    // ---- p-barrier (skip at t=0: p==0, all blocks agree) ----
    if (t > 0) {
      __syncthreads();                 // sl visible
      export_sl(pb + (size_t)par * 32 * HH);
      __syncthreads();                 // drains exports (vmcnt0 before s_barrier)
      ++ep;
      if (tid == 0)
        __hip_atomic_store(myf, ep, __ATOMIC_RELAXED, __HIP_MEMORY_SCOPE_AGENT);
    }
    if (t < TT - 1) stage(par ^ 1, t + 1);   // overlaps flag propagation
    // ---- phase B: h-part of n over p ----
    if (t > 0) {
      poll();
      v8s fr[16];
      load_frags16T(pb + (size_t)par * 32 * HH + q * 256 + arow * 8, fr);
#pragma unroll
      for (int ks = 0; ks < 16; ++ks) anc = MFMA(fr[ks], nb[ks], anc);
    }
    if (t == TT - 1) {
#pragma unroll
      for (int rg = 0; rg < 4; ++rg) {
        float n = tanh_f(anc[rg] + bnv);
        out[(size_t)(b0 + mrow + rg) * HH + ccol] = (1.f - zz[rg]) * h_own[rg] + zz[rg] * n;
      }
    } else {
#pragma unroll
      for (int rg = 0; rg < 4; ++rg) {
        float n = tanh_f(anc[rg] + bnv);
        float hn = (1.f - zz[rg]) * h_own[rg] + zz[rg] * n;
        float hd = __expf(-fmaxf(0.f, agc[rg] + bgv)) * hn;  // pre-apply gamma_h(t+1)
        h_own[rg] = hd;
        sl[(mrow + rg) * 36 + nh * 16 + ln] = f2b(hd);
      }
      __syncthreads();                 // sl visible
      export_sl(hb + (size_t)par * 32 * HH);
      __syncthreads();                 // drain exports
      ++ep;
      if (tid == 0)
        __hip_atomic_store(myf, ep, __ATOMIC_RELAXED, __HIP_MEMORY_SCOPE_AGENT);
      xgemm(par ^ 1);                  // x-part for t+1, overlaps flag propagation
      poll();                          // per-wave; next phase A starts immediately
    }
  }
}

extern "C" void kernel_launch(void* const* d_in, const int* in_sizes, int n_in,
                              void* d_out, int out_size, void* d_ws, size_t ws_size,
                              hipStream_t stream)
{
  const float* x   = (const float*)d_in[0];
  const float* xl  = (const float*)d_in[1];
  const float* mk  = (const float*)d_in[2];
  const float* de  = (const float*)d_in[3];
  const float* xm  = (const float*)d_in[4];
  const float* Wz  = (const float*)d_in[5];
  const float* bz  = (const float*)d_in[6];
  const float* Wr  = (const float*)d_in[7];
  const float* br  = (const float*)d_in[8];
  const float* Wn  = (const float*)d_in[9];
  const float* bn  = (const float*)d_in[10];
  const float* Wgx = (const float*)d_in[11];
  const float* bgx = (const float*)d_in[12];
  const float* Wgh = (const float*)d_in[13];
  const float* bgh = (const float*)d_in[14];
  float* out = (float*)d_out;

  char* p = (char*)d_ws;
  auto take = [&](size_t bytes) { char* r = p; p += (bytes + 255) & ~(size_t)255; return r; };
  unsigned short* PBUF = (unsigned short*)take((size_t)16 * 2 * 32 * HH * 2);  // 1 MB
  unsigned short* HBUF = (unsigned short*)take((size_t)16 * 2 * 32 * HH * 2);  // 1 MB
  unsigned int*   BARp = (unsigned int*)take(16 * 2048);                       // 32 KB

  hipMemsetAsync(BARp, 0, 16 * 2048, stream);

  k_seq<<<dim3(256), dim3(256), 0, stream>>>(
      x, xl, mk, de, xm, Wz, bz, Wr, br, Wn, bn,
      Wgx, bgx, Wgh, bgh, PBUF, HBUF, BARp, out);

  (void)in_sizes; (void)n_in; (void)out_size; (void)ws_size;
}